// Round 6
// baseline (242.797 us; speedup 1.0000x reference)
//
#include <hip/hip_runtime.h>
#include <hip/hip_bf16.h>

typedef unsigned short u16;
typedef short bf16x8 __attribute__((ext_vector_type(8)));
typedef float f32x4 __attribute__((ext_vector_type(4)));

__device__ __forceinline__ u16 f2bf(float f){
    unsigned u = __float_as_uint(f);
    unsigned r = 0x7fffu + ((u >> 16) & 1u);
    return (u16)((u + r) >> 16);
}

// ---------------- problem constants ----------------
// Inputs f32 (targets i32): noise(2,768,577) targets(2,384,384) w1(512,768,3,3)
// b1(512) w2(512,512,3,3) b2(512) w3(77) b3(77)
// Outputs f32: out0 transpose(noise) (577,2,768)=886272 ; out1 (2,77,171,512)=13483008
#define OUT0_N 886272
#define OUT1_N 13483008
#define YN 175104           // 342*512
#define KSPLIT 24           // gemm2 K-split: 4608/24 = 192

// ---------------- fused transpose: out0 (f32) + XbfT (bf16), LDS-tiled ----------------
__global__ void k_trans(const float* __restrict__ noise, float* __restrict__ out0,
                        u16* __restrict__ XbfT){
    __shared__ float tile[32][33];
    int s0 = blockIdx.x * 32;
    int c0 = blockIdx.y * 32;
    int b  = blockIdx.z;
    int tx = threadIdx.x, ty = threadIdx.y;   // (32, 8)
    #pragma unroll
    for (int i = 0; i < 4; i++){
        int c = c0 + ty + i * 8;
        int s = s0 + tx;
        if (s < 577) tile[ty + i * 8][tx] = noise[(size_t)(b * 768 + c) * 577 + s];
    }
    __syncthreads();
    #pragma unroll
    for (int i = 0; i < 4; i++){
        int s = s0 + ty + i * 8;
        int c = c0 + tx;
        if (s >= 577) continue;
        float v = tile[tx][ty + i * 8];
        out0[(size_t)(s * 2 + b) * 768 + c] = v;
        if (s >= 1) XbfT[(size_t)(b * 576 + s - 1) * 768 + c] = f2bf(v);
    }
}

// ---------------- Are[c1*9+tap][c0] bf16 ----------------
__global__ void k_prepA(const float* __restrict__ w1, u16* __restrict__ Are){
    int idx = blockIdx.x * 256 + threadIdx.x;    // 512*768
    if (idx >= 512 * 768) return;
    int k = idx % 768; int c1 = idx / 768;
    const float* wp = w1 + (size_t)idx * 9;
    #pragma unroll
    for (int tap = 0; tap < 9; tap++)
        Are[(size_t)(c1 * 9 + tap) * 768 + k] = f2bf(wp[tap]);
}

// ---------------- labels ----------------
__global__ void k_labels(const int* __restrict__ targets, int* __restrict__ labels){
    int idx = blockIdx.x * blockDim.x + threadIdx.x;   // 1152
    if (idx >= 1152) return;
    int b = idx / 576; int p = idx % 576;
    int i = p / 24, j = p % 24;
    labels[idx] = targets[b * 147456 + i * 16 * 384 + j * 16];
}

// ---------------- bias_eff[c2] = b2[c2] + (1/36)*sum_c1 b1[c1]*sum_taps w2*cnt ----------------
__global__ void k_bias(const float* __restrict__ w2, const float* __restrict__ b1,
                       const float* __restrict__ b2, float* __restrict__ bias){
    int c2 = blockIdx.x; int t = threadIdx.x;
    const float cw[9] = {25.f,30.f,25.f,30.f,36.f,30.f,25.f,30.f,25.f};
    float sb = 0.f;
    for (int c1 = t; c1 < 512; c1 += 256){
        const float* wp = w2 + (size_t)(c2 * 512 + c1) * 9;
        float s = 0.f;
        #pragma unroll
        for (int q = 0; q < 9; q++) s += wp[q] * cw[q];
        sb += b1[c1] * s;
    }
    __shared__ float red[256];
    red[t] = sb; __syncthreads();
    for (int o = 128; o > 0; o >>= 1){ if (t < o) red[t] += red[t + o]; __syncthreads(); }
    if (t == 0) bias[c2] = b2[c2] + red[0] * (1.0f / 36.0f);
}

// ---------------- Mfull[c2][c1*9 + rho*3+tau] ----------------
__global__ void k_Mfull(const float* __restrict__ w2, float* __restrict__ Mfull){
    int idx = blockIdx.x * 256 + threadIdx.x;   // 512*512
    if (idx >= 512 * 512) return;
    int c1 = idx % 512, c2 = idx / 512;
    const float* wp = w2 + (size_t)(c2 * 512 + c1) * 9;
    float t[3][3];
    #pragma unroll
    for (int r = 0; r < 3; r++)
        #pragma unroll
        for (int s = 0; s < 3; s++)
            t[r][s] = wp[r * 3 + s];
    float cs0[3], cs1[3], cs2[3];
    #pragma unroll
    for (int r = 0; r < 3; r++){
        cs0[r] = t[r][0] + t[r][1];
        cs1[r] = t[r][0] + t[r][1] + t[r][2];
        cs2[r] = t[r][1] + t[r][2];
    }
    const float inv = 1.0f / 576.0f;
    float* Mp = Mfull + (size_t)(c2 * 512 + c1) * 9;
    Mp[0] = inv * (cs0[0] + cs0[1]);
    Mp[1] = inv * (cs1[0] + cs1[1]);
    Mp[2] = inv * (cs2[0] + cs2[1]);
    Mp[3] = inv * (cs0[0] + cs0[1] + cs0[2]);
    Mp[4] = inv * (cs1[0] + cs1[1] + cs1[2]);
    Mp[5] = inv * (cs2[0] + cs2[1] + cs2[2]);
    Mp[6] = inv * (cs0[1] + cs0[2]);
    Mp[7] = inv * (cs1[1] + cs1[2]);
    Mp[8] = inv * (cs2[1] + cs2[2]);
}

// ---------------- GEMM1 (MFMA bf16, 3-stage reg pipeline): D = Are * XbfT^T ----------------
// Block 64m x 64n, 4 waves 2x2, wave tile 32m x 32n. Grid (72,18)=1296 blocks.
// Full K unroll (24 iters), loads for iter+2 in flight over MFMAs of iter.
__launch_bounds__(256)
__global__ void k_gemm1(const u16* __restrict__ Are, const u16* __restrict__ XbfT,
                        float* __restrict__ D){
    int wave = threadIdx.x >> 6;
    int lane = threadIdx.x & 63;
    int l16 = lane & 15, quad = lane >> 4;
    int wm = wave >> 1, wn = wave & 1;
    int m0 = blockIdx.x * 64 + wm * 32;
    int n0 = blockIdx.y * 64 + wn * 32;
    const u16* Ap = Are  + (size_t)(m0 + l16) * 768 + quad * 8;
    const u16* Bp = XbfT + (size_t)(n0 + l16) * 768 + quad * 8;
    f32x4 acc[2][2] = {};
    bf16x8 a[3][2], b[3][2];
    #pragma unroll
    for (int s = 0; s < 2; s++){
        #pragma unroll
        for (int i = 0; i < 2; i++){
            a[s][i] = *(const bf16x8*)(Ap + (size_t)i * 16 * 768 + s * 32);
            b[s][i] = *(const bf16x8*)(Bp + (size_t)i * 16 * 768 + s * 32);
        }
    }
    #pragma unroll
    for (int it = 0; it < 24; it++){
        int cur = it % 3;
        if (it < 22){
            int nxt = (it + 2) % 3;
            int k0 = (it + 2) * 32;
            #pragma unroll
            for (int i = 0; i < 2; i++){
                a[nxt][i] = *(const bf16x8*)(Ap + (size_t)i * 16 * 768 + k0);
                b[nxt][i] = *(const bf16x8*)(Bp + (size_t)i * 16 * 768 + k0);
            }
        }
        #pragma unroll
        for (int mi = 0; mi < 2; mi++)
            #pragma unroll
            for (int ni = 0; ni < 2; ni++)
                acc[mi][ni] = __builtin_amdgcn_mfma_f32_16x16x32_bf16(a[cur][mi], b[cur][ni], acc[mi][ni], 0, 0, 0);
    }
    // C/D layout: col(n) = lane&15, row(m) = quad*4 + reg
    #pragma unroll
    for (int mi = 0; mi < 2; mi++)
        #pragma unroll
        for (int ni = 0; ni < 2; ni++)
            #pragma unroll
            for (int r = 0; r < 4; r++)
                D[(size_t)(m0 + mi * 16 + quad * 4 + r) * 1152 + n0 + ni * 16 + l16] = acc[mi][ni][r];
}

// ---------------- scatter: one block per (b,c1); LDS class-histogram; plain stores ----------------
__launch_bounds__(256)
__global__ void k_scatter(const float* __restrict__ D, const int* __restrict__ labels,
                          float* __restrict__ Zcat){
    int blk = blockIdx.x;            // 0..1023
    int b  = blk >> 9;
    int c1 = blk & 511;
    __shared__ float acc[171 * 9];
    int t = threadIdx.x;
    for (int q = t; q < 1539; q += 256) acc[q] = 0.f;
    __syncthreads();
    for (int p = t; p < 576; p += 256){
        int cls = labels[b * 576 + p];
        if (cls < 0 || cls >= 171) continue;
        int i = p / 24, j = p % 24;
        float slot[9];
        #pragma unroll
        for (int q = 0; q < 9; q++) slot[q] = 0.f;
        unsigned used = 0;
        int tau[3]; bool vs[3];
        #pragma unroll
        for (int s1 = 0; s1 < 3; s1++){
            int v = j - s1 + 1;
            vs[s1]  = (v >= 0 && v < 24);
            tau[s1] = (v < 4) ? 0 : ((v < 20) ? 1 : 2);
        }
        #pragma unroll
        for (int r1 = 0; r1 < 3; r1++){
            int u = i - r1 + 1;
            if (u < 0 || u >= 24) continue;
            int rho = (u < 4) ? 0 : ((u < 20) ? 1 : 2);
            #pragma unroll
            for (int s1 = 0; s1 < 3; s1++){
                if (!vs[s1]) continue;
                float tv = D[(size_t)(c1 * 9 + r1 * 3 + s1) * 1152 + b * 576 + p];
                int sl = rho * 3 + tau[s1];
                slot[sl] += tv;
                used |= 1u << sl;
            }
        }
        #pragma unroll
        for (int sl = 0; sl < 9; sl++)
            if (used & (1u << sl)) atomicAdd(&acc[cls * 9 + sl], slot[sl]);
    }
    __syncthreads();
    for (int q = t; q < 1539; q += 256){
        int cls = q / 9, sl = q % 9;
        Zcat[(size_t)(b * 171 + cls) * 4608 + c1 * 9 + sl] = acc[q];
    }
}

// ---------------- GEMM2 phase A: ypart[s][n][c2] partial over K-chunk 192 ----------------
__launch_bounds__(256)
__global__ void k_gemm2p(const float* __restrict__ Mfull, const float* __restrict__ Zcat,
                         float* __restrict__ ypart){
    __shared__ __align__(16) float As[16][68];
    __shared__ __align__(16) float Bs[16][68];
    int m0 = blockIdx.x * 64;   // c2
    int n0 = blockIdx.y * 64;   // n2
    int s  = blockIdx.z;
    int kbeg = s * 192;
    int t  = threadIdx.x;
    int tx = t % 16, ty = t / 16;
    float acc[4][4] = {};
    for (int k0 = kbeg; k0 < kbeg + 192; k0 += 16){
        #pragma unroll
        for (int e = t; e < 1024; e += 256){
            int r = e / 16, c = e % 16;
            As[c][r] = Mfull[(size_t)(m0 + r) * 4608 + k0 + c];
        }
        #pragma unroll
        for (int e = t; e < 1024; e += 256){
            int r = e / 16, c = e % 16;
            int n = n0 + r;
            Bs[c][r] = (n < 342) ? Zcat[(size_t)n * 4608 + k0 + c] : 0.f;
        }
        __syncthreads();
        #pragma unroll
        for (int kk = 0; kk < 16; kk++){
            float4 a4 = *(const float4*)&As[kk][ty * 4];
            float4 b4 = *(const float4*)&Bs[kk][tx * 4];
            float a[4] = {a4.x, a4.y, a4.z, a4.w};
            float bb[4] = {b4.x, b4.y, b4.z, b4.w};
            #pragma unroll
            for (int mi = 0; mi < 4; mi++)
                #pragma unroll
                for (int ni = 0; ni < 4; ni++)
                    acc[mi][ni] += a[mi] * bb[ni];
        }
        __syncthreads();
    }
    float* yp = ypart + (size_t)s * YN;
    #pragma unroll
    for (int ni = 0; ni < 4; ni++){
        int n = n0 + tx * 4 + ni;
        if (n >= 342) continue;
        float4 v = make_float4(acc[0][ni], acc[1][ni], acc[2][ni], acc[3][ni]);
        *(float4*)&yp[(size_t)n * 512 + m0 + ty * 4] = v;
    }
}

// ---------------- GEMM2 reduce: y = sum_s ypart + bias ----------------
__global__ void k_gemm2r(const float* __restrict__ ypart, const float* __restrict__ bias,
                         float* __restrict__ y){
    int idx = blockIdx.x * 256 + threadIdx.x;   // 175104
    if (idx >= YN) return;
    float sum = bias[idx & 511];
    #pragma unroll 4
    for (int s = 0; s < KSPLIT; s++) sum += ypart[(size_t)s * YN + idx];
    y[idx] = sum;
}

// ---------------- final: out1[b,o,cls,c] = w3[o]*y[b*171+cls][c] + b3[o], float4 ----------------
__global__ void k_final(const float* __restrict__ y, const float* __restrict__ w3,
                        const float* __restrict__ b3, float4* __restrict__ out1){
    int idx = blockIdx.x * 256 + threadIdx.x;   // OUT1_N/4 = 3370752
    if (idx >= OUT1_N / 4) return;
    int c4 = idx & 127;
    int r = idx >> 7;
    int cls = r % 171; r /= 171;
    int o = r % 77;
    int b = r / 77;
    float4 v = *(const float4*)&y[(size_t)(b * 171 + cls) * 512 + c4 * 4];
    float w = w3[o], bb = b3[o];
    out1[idx] = make_float4(w * v.x + bb, w * v.y + bb, w * v.z + bb, w * v.w + bb);
}

extern "C" void kernel_launch(void* const* d_in, const int* in_sizes, int n_in,
                              void* d_out, int out_size, void* d_ws, size_t ws_size,
                              hipStream_t stream) {
    const float* noise   = (const float*)d_in[0];
    const int*   targets = (const int*)  d_in[1];
    const float* w1      = (const float*)d_in[2];
    const float* b1      = (const float*)d_in[3];
    const float* w2      = (const float*)d_in[4];
    const float* b2      = (const float*)d_in[5];
    const float* w3      = (const float*)d_in[6];
    const float* b3      = (const float*)d_in[7];
    float* out0 = (float*)d_out;
    float* out1 = out0 + OUT0_N;

    char* ws = (char*)d_ws;
    const size_t OFF_ARE  = 0;                        // 7,077,888
    const size_t OFF_X    = 7077888;                  // 1,769,472
    const size_t OFF_D    = OFF_X   + 1769472;        // 21,233,664 (reused as ypart)
    const size_t OFF_MF   = OFF_D   + 21233664;       // 9,437,184
    const size_t OFF_ZC   = OFF_MF  + 9437184;        // 6,303,744
    const size_t OFF_Y    = OFF_ZC  + 6303744;        // 700,416
    const size_t OFF_BIAS = OFF_Y   + 700416;         // 2048
    const size_t OFF_LAB  = OFF_BIAS + 2048;          // 4608

    u16*   Are   = (u16*)  (ws + OFF_ARE);
    u16*   XbfT  = (u16*)  (ws + OFF_X);
    float* D     = (float*)(ws + OFF_D);
    float* ypart = (float*)(ws + OFF_D);              // alias: D dead after k_scatter
    float* Mfull = (float*)(ws + OFF_MF);
    float* Zcat  = (float*)(ws + OFF_ZC);
    float* yb    = (float*)(ws + OFF_Y);
    float* bias  = (float*)(ws + OFF_BIAS);
    int*   labels= (int*)  (ws + OFF_LAB);

    k_bias  <<<512, 256, 0, stream>>>(w2, b1, b2, bias);
    k_labels<<<5, 256, 0, stream>>>(targets, labels);
    k_trans <<<dim3(19, 24, 2), dim3(32, 8), 0, stream>>>(noise, out0, XbfT);
    k_prepA <<<(512 * 768) / 256, 256, 0, stream>>>(w1, Are);
    k_Mfull <<<(512 * 512) / 256, 256, 0, stream>>>(w2, Mfull);
    k_gemm1 <<<dim3(72, 18), 256, 0, stream>>>(Are, XbfT, D);
    k_scatter<<<1024, 256, 0, stream>>>(D, labels, Zcat);
    k_gemm2p<<<dim3(8, 6, KSPLIT), 256, 0, stream>>>(Mfull, Zcat, ypart);
    k_gemm2r<<<(YN + 255) / 256, 256, 0, stream>>>(ypart, bias, yb);
    k_final <<<(OUT1_N / 4 + 255) / 256, 256, 0, stream>>>(yb, w3, b3, (float4*)out1);
}

// Round 7
// 189.656 us; speedup vs baseline: 1.2802x; 1.2802x over previous
//
#include <hip/hip_runtime.h>
#include <hip/hip_bf16.h>

typedef unsigned short u16;
typedef short bf16x8 __attribute__((ext_vector_type(8)));
typedef float f32x4 __attribute__((ext_vector_type(4)));

__device__ __forceinline__ u16 f2bf(float f){
    unsigned u = __float_as_uint(f);
    unsigned r = 0x7fffu + ((u >> 16) & 1u);
    return (u16)((u + r) >> 16);
}

// async global->LDS, 16B per lane; LDS dest must be wave-uniform base + lane*16
__device__ __forceinline__ void gload_lds16(const u16* g, u16* lds_base){
    __builtin_amdgcn_global_load_lds(
        (const __attribute__((address_space(1))) unsigned int*)g,
        (__attribute__((address_space(3))) unsigned int*)lds_base, 16, 0, 0);
}

// ---------------- problem constants ----------------
// Inputs f32 (targets i32): noise(2,768,577) targets(2,384,384) w1(512,768,3,3)
// b1(512) w2(512,512,3,3) b2(512) w3(77) b3(77)
// Outputs f32: out0 transpose(noise) (577,2,768)=886272 ; out1 (2,77,171,512)=13483008
#define OUT0_N 886272
#define OUT1_N 13483008
#define YN 175104           // 342*512
#define KSPLIT 24           // gemm2 K-split: 4608/24 = 192

// ---------------- fused prep: trans(912) | prepA(1536) | Mfull(1024) | bias(512) | labels(5) ----------------
__global__ void k_prep(const float* __restrict__ noise, const int* __restrict__ targets,
                       const float* __restrict__ w1, const float* __restrict__ b1,
                       const float* __restrict__ w2, const float* __restrict__ b2,
                       float* __restrict__ out0, u16* __restrict__ XbfT,
                       u16* __restrict__ Are, float* __restrict__ Mfull,
                       float* __restrict__ bias, int* __restrict__ labels){
    __shared__ float sh[32 * 33];
    int blk = blockIdx.x;
    int tid = threadIdx.x;
    if (blk < 912){
        // transpose: out0 (f32) + XbfT (bf16)
        int b   = blk / 456;           // 19*24
        int rem = blk % 456;
        int cb  = rem / 19, sb = rem % 19;
        int tx = tid & 31, ty = tid >> 5;      // 32 x 8
        int s0 = sb * 32, c0 = cb * 32;
        float (*tile)[33] = (float(*)[33])sh;
        #pragma unroll
        for (int i = 0; i < 4; i++){
            int c = c0 + ty + i * 8;
            int s = s0 + tx;
            if (s < 577) tile[ty + i * 8][tx] = noise[(size_t)(b * 768 + c) * 577 + s];
        }
        __syncthreads();
        #pragma unroll
        for (int i = 0; i < 4; i++){
            int s = s0 + ty + i * 8;
            int c = c0 + tx;
            if (s >= 577) continue;
            float v = tile[tx][ty + i * 8];
            out0[(size_t)(s * 2 + b) * 768 + c] = v;
            if (s >= 1) XbfT[(size_t)(b * 576 + s - 1) * 768 + c] = f2bf(v);
        }
    } else if (blk < 2448){
        // prepA: Are[c1*9+tap][c0] bf16
        int idx = (blk - 912) * 256 + tid;     // < 512*768
        int k = idx % 768; int c1 = idx / 768;
        const float* wp = w1 + (size_t)idx * 9;
        #pragma unroll
        for (int tap = 0; tap < 9; tap++)
            Are[(size_t)(c1 * 9 + tap) * 768 + k] = f2bf(wp[tap]);
    } else if (blk < 3472){
        // Mfull[c2][c1*9 + rho*3+tau]
        int idx = (blk - 2448) * 256 + tid;    // < 512*512
        int c1 = idx % 512, c2 = idx / 512;
        const float* wp = w2 + (size_t)(c2 * 512 + c1) * 9;
        float t[3][3];
        #pragma unroll
        for (int r = 0; r < 3; r++)
            #pragma unroll
            for (int s = 0; s < 3; s++)
                t[r][s] = wp[r * 3 + s];
        float cs0[3], cs1[3], cs2[3];
        #pragma unroll
        for (int r = 0; r < 3; r++){
            cs0[r] = t[r][0] + t[r][1];
            cs1[r] = t[r][0] + t[r][1] + t[r][2];
            cs2[r] = t[r][1] + t[r][2];
        }
        const float inv = 1.0f / 576.0f;
        float* Mp = Mfull + (size_t)(c2 * 512 + c1) * 9;
        Mp[0] = inv * (cs0[0] + cs0[1]);
        Mp[1] = inv * (cs1[0] + cs1[1]);
        Mp[2] = inv * (cs2[0] + cs2[1]);
        Mp[3] = inv * (cs0[0] + cs0[1] + cs0[2]);
        Mp[4] = inv * (cs1[0] + cs1[1] + cs1[2]);
        Mp[5] = inv * (cs2[0] + cs2[1] + cs2[2]);
        Mp[6] = inv * (cs0[1] + cs0[2]);
        Mp[7] = inv * (cs1[1] + cs1[2]);
        Mp[8] = inv * (cs2[1] + cs2[2]);
    } else if (blk < 3984){
        // bias_eff[c2] = b2[c2] + (1/36)*sum_c1 b1[c1]*sum_taps w2*cnt
        int c2 = blk - 3472;
        const float cw[9] = {25.f,30.f,25.f,30.f,36.f,30.f,25.f,30.f,25.f};
        float sb = 0.f;
        for (int c1 = tid; c1 < 512; c1 += 256){
            const float* wp = w2 + (size_t)(c2 * 512 + c1) * 9;
            float s = 0.f;
            #pragma unroll
            for (int q = 0; q < 9; q++) s += wp[q] * cw[q];
            sb += b1[c1] * s;
        }
        sh[tid] = sb; __syncthreads();
        for (int o = 128; o > 0; o >>= 1){ if (tid < o) sh[tid] += sh[tid + o]; __syncthreads(); }
        if (tid == 0) bias[c2] = b2[c2] + sh[0] * (1.0f / 36.0f);
    } else {
        // labels
        int idx = (blk - 3984) * 256 + tid;
        if (idx < 1152){
            int b = idx / 576; int p = idx % 576;
            int i = p / 24, j = p % 24;
            labels[idx] = targets[b * 147456 + i * 16 * 384 + j * 16];
        }
    }
}

// ---------------- GEMM1 (m97-style LDS-staged MFMA): D[4608][1152] = Are * XbfT^T ----------------
// Block 128m x 64n, BK=64, 4 waves 2x2 (wave tile 64m x 32n). Grid (36,18)=648.
// global_load_lds 16B staging; LDS layout [row][k] k-contig matches lane*16 scatter.
__launch_bounds__(256)
__global__ void k_gemm1(const u16* __restrict__ Are, const u16* __restrict__ XbfT,
                        float* __restrict__ D){
    __shared__ u16 As[128 * 64];   // 16 KB, [m][k]
    __shared__ u16 Bs[64 * 64];    // 8 KB,  [n][k]
    int tid  = threadIdx.x;
    int wave = tid >> 6, lane = tid & 63;
    int l16 = lane & 15, quad = lane >> 4;
    int wm = wave >> 1, wn = wave & 1;
    int m0 = blockIdx.x * 128;
    int n0 = blockIdx.y * 64;
    int srow = lane >> 3, scol = (lane & 7) * 8;   // staging: 8 rows x 64k per chunk
    f32x4 acc[4][2] = {};
    for (int k0 = 0; k0 < 768; k0 += 64){
        #pragma unroll
        for (int j = 0; j < 4; j++){               // A: 16 chunks, 4 per wave
            int ch = wave * 4 + j;
            gload_lds16(Are + (size_t)(m0 + ch * 8 + srow) * 768 + k0 + scol, &As[ch * 512]);
        }
        #pragma unroll
        for (int j = 0; j < 2; j++){               // B: 8 chunks, 2 per wave
            int ch = wave * 2 + j;
            gload_lds16(XbfT + (size_t)(n0 + ch * 8 + srow) * 768 + k0 + scol, &Bs[ch * 512]);
        }
        __syncthreads();                           // drains vmcnt, publishes LDS
        #pragma unroll
        for (int ks = 0; ks < 2; ks++){
            bf16x8 af[4], bf[2];
            #pragma unroll
            for (int i = 0; i < 4; i++)
                af[i] = *(const bf16x8*)&As[(wm * 64 + i * 16 + l16) * 64 + ks * 32 + quad * 8];
            #pragma unroll
            for (int i = 0; i < 2; i++)
                bf[i] = *(const bf16x8*)&Bs[(wn * 32 + i * 16 + l16) * 64 + ks * 32 + quad * 8];
            #pragma unroll
            for (int mi = 0; mi < 4; mi++)
                #pragma unroll
                for (int ni = 0; ni < 2; ni++)
                    acc[mi][ni] = __builtin_amdgcn_mfma_f32_16x16x32_bf16(af[mi], bf[ni], acc[mi][ni], 0, 0, 0);
        }
        __syncthreads();                           // before overwriting LDS
    }
    // C/D layout: col(n) = lane&15, row(m) = quad*4 + reg
    #pragma unroll
    for (int mi = 0; mi < 4; mi++)
        #pragma unroll
        for (int ni = 0; ni < 2; ni++)
            #pragma unroll
            for (int r = 0; r < 4; r++)
                D[(size_t)(m0 + wm * 64 + mi * 16 + quad * 4 + r) * 1152 + n0 + wn * 32 + ni * 16 + l16] = acc[mi][ni][r];
}

// ---------------- scatter: one block per (b,c1); LDS class-histogram; plain stores ----------------
__launch_bounds__(256)
__global__ void k_scatter(const float* __restrict__ D, const int* __restrict__ labels,
                          float* __restrict__ Zcat){
    int blk = blockIdx.x;            // 0..1023
    int b  = blk >> 9;
    int c1 = blk & 511;
    __shared__ float acc[171 * 9];
    int t = threadIdx.x;
    for (int q = t; q < 1539; q += 256) acc[q] = 0.f;
    __syncthreads();
    for (int p = t; p < 576; p += 256){
        int cls = labels[b * 576 + p];
        if (cls < 0 || cls >= 171) continue;
        int i = p / 24, j = p % 24;
        float slot[9];
        #pragma unroll
        for (int q = 0; q < 9; q++) slot[q] = 0.f;
        unsigned used = 0;
        int tau[3]; bool vs[3];
        #pragma unroll
        for (int s1 = 0; s1 < 3; s1++){
            int v = j - s1 + 1;
            vs[s1]  = (v >= 0 && v < 24);
            tau[s1] = (v < 4) ? 0 : ((v < 20) ? 1 : 2);
        }
        #pragma unroll
        for (int r1 = 0; r1 < 3; r1++){
            int u = i - r1 + 1;
            if (u < 0 || u >= 24) continue;
            int rho = (u < 4) ? 0 : ((u < 20) ? 1 : 2);
            #pragma unroll
            for (int s1 = 0; s1 < 3; s1++){
                if (!vs[s1]) continue;
                float tv = D[(size_t)(c1 * 9 + r1 * 3 + s1) * 1152 + b * 576 + p];
                int sl = rho * 3 + tau[s1];
                slot[sl] += tv;
                used |= 1u << sl;
            }
        }
        #pragma unroll
        for (int sl = 0; sl < 9; sl++)
            if (used & (1u << sl)) atomicAdd(&acc[cls * 9 + sl], slot[sl]);
    }
    __syncthreads();
    for (int q = t; q < 1539; q += 256){
        int cls = q / 9, sl = q % 9;
        Zcat[(size_t)(b * 171 + cls) * 4608 + c1 * 9 + sl] = acc[q];
    }
}

// ---------------- GEMM2 phase A: ypart[s][n][c2] partial over K-chunk 192 ----------------
__launch_bounds__(256)
__global__ void k_gemm2p(const float* __restrict__ Mfull, const float* __restrict__ Zcat,
                         float* __restrict__ ypart){
    __shared__ __align__(16) float As[16][68];
    __shared__ __align__(16) float Bs[16][68];
    int m0 = blockIdx.x * 64;   // c2
    int n0 = blockIdx.y * 64;   // n2
    int s  = blockIdx.z;
    int kbeg = s * 192;
    int t  = threadIdx.x;
    int tx = t % 16, ty = t / 16;
    float acc[4][4] = {};
    for (int k0 = kbeg; k0 < kbeg + 192; k0 += 16){
        #pragma unroll
        for (int e = t; e < 1024; e += 256){
            int r = e / 16, c = e % 16;
            As[c][r] = Mfull[(size_t)(m0 + r) * 4608 + k0 + c];
        }
        #pragma unroll
        for (int e = t; e < 1024; e += 256){
            int r = e / 16, c = e % 16;
            int n = n0 + r;
            Bs[c][r] = (n < 342) ? Zcat[(size_t)n * 4608 + k0 + c] : 0.f;
        }
        __syncthreads();
        #pragma unroll
        for (int kk = 0; kk < 16; kk++){
            float4 a4 = *(const float4*)&As[kk][ty * 4];
            float4 b4 = *(const float4*)&Bs[kk][tx * 4];
            float a[4] = {a4.x, a4.y, a4.z, a4.w};
            float bb[4] = {b4.x, b4.y, b4.z, b4.w};
            #pragma unroll
            for (int mi = 0; mi < 4; mi++)
                #pragma unroll
                for (int ni = 0; ni < 4; ni++)
                    acc[mi][ni] += a[mi] * bb[ni];
        }
        __syncthreads();
    }
    float* yp = ypart + (size_t)s * YN;
    #pragma unroll
    for (int ni = 0; ni < 4; ni++){
        int n = n0 + tx * 4 + ni;
        if (n >= 342) continue;
        float4 v = make_float4(acc[0][ni], acc[1][ni], acc[2][ni], acc[3][ni]);
        *(float4*)&yp[(size_t)n * 512 + m0 + ty * 4] = v;
    }
}

// ---------------- GEMM2 reduce: y = sum_s ypart + bias ----------------
__global__ void k_gemm2r(const float* __restrict__ ypart, const float* __restrict__ bias,
                         float* __restrict__ y){
    int idx = blockIdx.x * 256 + threadIdx.x;   // 175104
    if (idx >= YN) return;
    float sum = bias[idx & 511];
    #pragma unroll 4
    for (int s = 0; s < KSPLIT; s++) sum += ypart[(size_t)s * YN + idx];
    y[idx] = sum;
}

// ---------------- final: out1[b,o,cls,c] = w3[o]*y[b*171+cls][c] + b3[o], float4 ----------------
__global__ void k_final(const float* __restrict__ y, const float* __restrict__ w3,
                        const float* __restrict__ b3, float4* __restrict__ out1){
    int idx = blockIdx.x * 256 + threadIdx.x;   // OUT1_N/4 = 3370752
    if (idx >= OUT1_N / 4) return;
    int c4 = idx & 127;
    int r = idx >> 7;
    int cls = r % 171; r /= 171;
    int o = r % 77;
    int b = r / 77;
    float4 v = *(const float4*)&y[(size_t)(b * 171 + cls) * 512 + c4 * 4];
    float w = w3[o], bb = b3[o];
    out1[idx] = make_float4(w * v.x + bb, w * v.y + bb, w * v.z + bb, w * v.w + bb);
}

extern "C" void kernel_launch(void* const* d_in, const int* in_sizes, int n_in,
                              void* d_out, int out_size, void* d_ws, size_t ws_size,
                              hipStream_t stream) {
    const float* noise   = (const float*)d_in[0];
    const int*   targets = (const int*)  d_in[1];
    const float* w1      = (const float*)d_in[2];
    const float* b1      = (const float*)d_in[3];
    const float* w2      = (const float*)d_in[4];
    const float* b2      = (const float*)d_in[5];
    const float* w3      = (const float*)d_in[6];
    const float* b3      = (const float*)d_in[7];
    float* out0 = (float*)d_out;
    float* out1 = out0 + OUT0_N;

    char* ws = (char*)d_ws;
    const size_t OFF_ARE  = 0;                        // 7,077,888
    const size_t OFF_X    = 7077888;                  // 1,769,472
    const size_t OFF_D    = OFF_X   + 1769472;        // 21,233,664 (reused as ypart)
    const size_t OFF_MF   = OFF_D   + 21233664;       // 9,437,184
    const size_t OFF_ZC   = OFF_MF  + 9437184;        // 6,303,744
    const size_t OFF_Y    = OFF_ZC  + 6303744;        // 700,416
    const size_t OFF_BIAS = OFF_Y   + 700416;         // 2048
    const size_t OFF_LAB  = OFF_BIAS + 2048;          // 4608

    u16*   Are   = (u16*)  (ws + OFF_ARE);
    u16*   XbfT  = (u16*)  (ws + OFF_X);
    float* D     = (float*)(ws + OFF_D);
    float* ypart = (float*)(ws + OFF_D);              // alias: D dead after k_scatter
    float* Mfull = (float*)(ws + OFF_MF);
    float* Zcat  = (float*)(ws + OFF_ZC);
    float* yb    = (float*)(ws + OFF_Y);
    float* bias  = (float*)(ws + OFF_BIAS);
    int*   labels= (int*)  (ws + OFF_LAB);

    k_prep  <<<3989, 256, 0, stream>>>(noise, targets, w1, b1, w2, b2,
                                       out0, XbfT, Are, Mfull, bias, labels);
    k_gemm1 <<<dim3(36, 18), 256, 0, stream>>>(Are, XbfT, D);
    k_scatter<<<1024, 256, 0, stream>>>(D, labels, Zcat);
    k_gemm2p<<<dim3(8, 6, KSPLIT), 256, 0, stream>>>(Mfull, Zcat, ypart);
    k_gemm2r<<<(YN + 255) / 256, 256, 0, stream>>>(ypart, bias, yb);
    k_final <<<(OUT1_N / 4 + 255) / 256, 256, 0, stream>>>(yb, w3, b3, (float4*)out1);
}

// Round 8
// 158.664 us; speedup vs baseline: 1.5303x; 1.1953x over previous
//
#include <hip/hip_runtime.h>
#include <hip/hip_bf16.h>

typedef unsigned short u16;
typedef short bf16x8 __attribute__((ext_vector_type(8)));
typedef float f32x4 __attribute__((ext_vector_type(4)));

__device__ __forceinline__ u16 f2bf(float f){
    unsigned u = __float_as_uint(f);
    unsigned r = 0x7fffu + ((u >> 16) & 1u);
    return (u16)((u + r) >> 16);
}

// async global->LDS, 16B per lane; LDS dest = wave-uniform base + lane*16
__device__ __forceinline__ void gload_lds16(const u16* g, u16* lds_base){
    __builtin_amdgcn_global_load_lds(
        (const __attribute__((address_space(1))) unsigned int*)g,
        (__attribute__((address_space(3))) unsigned int*)lds_base, 16, 0, 0);
}

// ---------------- problem constants ----------------
// Inputs f32 (targets i32): noise(2,768,577) targets(2,384,384) w1(512,768,3,3)
// b1(512) w2(512,512,3,3) b2(512) w3(77) b3(77)
// Outputs f32: out0 (577,2,768)=886272 ; out1 (2,77,171,512)=13483008
#define OUT0_N 886272
#define OUT1_N 13483008
#define YN 175104           // 342*512
#define KS2 24              // gemm2 K-split: 4608/24 = 192

// ---------------- fused prep ----------------
// blocks: trans(912) | prepA(1536) | Mfull16(1024) | bias(512) | labels(5) | Zcat pad zero(756)
__global__ void k_prep(const float* __restrict__ noise, const int* __restrict__ targets,
                       const float* __restrict__ w1, const float* __restrict__ b1,
                       const float* __restrict__ w2, const float* __restrict__ b2,
                       float* __restrict__ out0, u16* __restrict__ XbfT,
                       u16* __restrict__ Are, u16* __restrict__ Mfull16,
                       float* __restrict__ bias, int* __restrict__ labels,
                       u16* __restrict__ Zcat16){
    __shared__ float sh[32 * 33];
    int blk = blockIdx.x;
    int tid = threadIdx.x;
    if (blk < 912){
        int b   = blk / 456;           // 19*24
        int rem = blk % 456;
        int cb  = rem / 19, sb = rem % 19;
        int tx = tid & 31, ty = tid >> 5;      // 32 x 8
        int s0 = sb * 32, c0 = cb * 32;
        float (*tile)[33] = (float(*)[33])sh;
        #pragma unroll
        for (int i = 0; i < 4; i++){
            int c = c0 + ty + i * 8;
            int s = s0 + tx;
            if (s < 577) tile[ty + i * 8][tx] = noise[(size_t)(b * 768 + c) * 577 + s];
        }
        __syncthreads();
        #pragma unroll
        for (int i = 0; i < 4; i++){
            int s = s0 + ty + i * 8;
            int c = c0 + tx;
            if (s >= 577) continue;
            float v = tile[tx][ty + i * 8];
            out0[(size_t)(s * 2 + b) * 768 + c] = v;
            if (s >= 1) XbfT[(size_t)(b * 576 + s - 1) * 768 + c] = f2bf(v);
        }
    } else if (blk < 2448){
        int idx = (blk - 912) * 256 + tid;     // < 512*768
        int k = idx % 768; int c1 = idx / 768;
        const float* wp = w1 + (size_t)idx * 9;
        #pragma unroll
        for (int tap = 0; tap < 9; tap++)
            Are[(size_t)(c1 * 9 + tap) * 768 + k] = f2bf(wp[tap]);
    } else if (blk < 3472){
        int idx = (blk - 2448) * 256 + tid;    // < 512*512
        int c1 = idx % 512, c2 = idx / 512;
        const float* wp = w2 + (size_t)(c2 * 512 + c1) * 9;
        float t[3][3];
        #pragma unroll
        for (int r = 0; r < 3; r++)
            #pragma unroll
            for (int s = 0; s < 3; s++)
                t[r][s] = wp[r * 3 + s];
        float cs0[3], cs1[3], cs2[3];
        #pragma unroll
        for (int r = 0; r < 3; r++){
            cs0[r] = t[r][0] + t[r][1];
            cs1[r] = t[r][0] + t[r][1] + t[r][2];
            cs2[r] = t[r][1] + t[r][2];
        }
        const float inv = 1.0f / 576.0f;
        u16* Mp = Mfull16 + (size_t)(c2 * 512 + c1) * 9;
        Mp[0] = f2bf(inv * (cs0[0] + cs0[1]));
        Mp[1] = f2bf(inv * (cs1[0] + cs1[1]));
        Mp[2] = f2bf(inv * (cs2[0] + cs2[1]));
        Mp[3] = f2bf(inv * (cs0[0] + cs0[1] + cs0[2]));
        Mp[4] = f2bf(inv * (cs1[0] + cs1[1] + cs1[2]));
        Mp[5] = f2bf(inv * (cs2[0] + cs2[1] + cs2[2]));
        Mp[6] = f2bf(inv * (cs0[1] + cs0[2]));
        Mp[7] = f2bf(inv * (cs1[1] + cs1[2]));
        Mp[8] = f2bf(inv * (cs2[1] + cs2[2]));
    } else if (blk < 3984){
        int c2 = blk - 3472;
        const float cw[9] = {25.f,30.f,25.f,30.f,36.f,30.f,25.f,30.f,25.f};
        float sb = 0.f;
        for (int c1 = tid; c1 < 512; c1 += 256){
            const float* wp = w2 + (size_t)(c2 * 512 + c1) * 9;
            float s = 0.f;
            #pragma unroll
            for (int q = 0; q < 9; q++) s += wp[q] * cw[q];
            sb += b1[c1] * s;
        }
        sh[tid] = sb; __syncthreads();
        for (int o = 128; o > 0; o >>= 1){ if (tid < o) sh[tid] += sh[tid + o]; __syncthreads(); }
        if (tid == 0) bias[c2] = b2[c2] + sh[0] * (1.0f / 36.0f);
    } else if (blk < 3989){
        int idx = (blk - 3984) * 256 + tid;
        if (idx < 1152){
            int b = idx / 576; int p = idx % 576;
            int i = p / 24, j = p % 24;
            labels[idx] = targets[b * 147456 + i * 16 * 384 + j * 16];
        }
    } else {
        // zero Zcat pad rows 342..383 (42*4608 = 193536 u16)
        int idx = (blk - 3989) * 256 + tid;
        if (idx < 193536) Zcat16[342 * 4608 + idx] = 0;
    }
}

// ---------------- GEMM1 (LDS-staged MFMA): D[4608][1152] = Are * XbfT^T ----------------
__launch_bounds__(256)
__global__ void k_gemm1(const u16* __restrict__ Are, const u16* __restrict__ XbfT,
                        float* __restrict__ D){
    __shared__ u16 As[128 * 64];   // [m][k]
    __shared__ u16 Bs[64 * 64];    // [n][k]
    int tid  = threadIdx.x;
    int wave = tid >> 6, lane = tid & 63;
    int l16 = lane & 15, quad = lane >> 4;
    int wm = wave >> 1, wn = wave & 1;
    int m0 = blockIdx.x * 128;
    int n0 = blockIdx.y * 64;
    int srow = lane >> 3, scol = (lane & 7) * 8;
    f32x4 acc[4][2] = {};
    for (int k0 = 0; k0 < 768; k0 += 64){
        #pragma unroll
        for (int j = 0; j < 4; j++){
            int ch = wave * 4 + j;
            gload_lds16(Are + (size_t)(m0 + ch * 8 + srow) * 768 + k0 + scol, &As[ch * 512]);
        }
        #pragma unroll
        for (int j = 0; j < 2; j++){
            int ch = wave * 2 + j;
            gload_lds16(XbfT + (size_t)(n0 + ch * 8 + srow) * 768 + k0 + scol, &Bs[ch * 512]);
        }
        __syncthreads();
        #pragma unroll
        for (int ks = 0; ks < 2; ks++){
            bf16x8 af[4], bf[2];
            #pragma unroll
            for (int i = 0; i < 4; i++)
                af[i] = *(const bf16x8*)&As[(wm * 64 + i * 16 + l16) * 64 + ks * 32 + quad * 8];
            #pragma unroll
            for (int i = 0; i < 2; i++)
                bf[i] = *(const bf16x8*)&Bs[(wn * 32 + i * 16 + l16) * 64 + ks * 32 + quad * 8];
            #pragma unroll
            for (int mi = 0; mi < 4; mi++)
                #pragma unroll
                for (int ni = 0; ni < 2; ni++)
                    acc[mi][ni] = __builtin_amdgcn_mfma_f32_16x16x32_bf16(af[mi], bf[ni], acc[mi][ni], 0, 0, 0);
        }
        __syncthreads();
    }
    #pragma unroll
    for (int mi = 0; mi < 4; mi++)
        #pragma unroll
        for (int ni = 0; ni < 2; ni++)
            #pragma unroll
            for (int r = 0; r < 4; r++)
                D[(size_t)(m0 + wm * 64 + mi * 16 + quad * 4 + r) * 1152 + n0 + wn * 32 + ni * 16 + l16] = acc[mi][ni][r];
}

// ---------------- scatter: one block per (b,c1); LDS class-histogram; bf16 stores ----------------
__launch_bounds__(256)
__global__ void k_scatter(const float* __restrict__ D, const int* __restrict__ labels,
                          u16* __restrict__ Zcat16){
    int blk = blockIdx.x;            // 0..1023
    int b  = blk >> 9;
    int c1 = blk & 511;
    __shared__ float acc[171 * 9];
    int t = threadIdx.x;
    for (int q = t; q < 1539; q += 256) acc[q] = 0.f;
    __syncthreads();
    for (int p = t; p < 576; p += 256){
        int cls = labels[b * 576 + p];
        if (cls < 0 || cls >= 171) continue;
        int i = p / 24, j = p % 24;
        float slot[9];
        #pragma unroll
        for (int q = 0; q < 9; q++) slot[q] = 0.f;
        unsigned used = 0;
        int tau[3]; bool vs[3];
        #pragma unroll
        for (int s1 = 0; s1 < 3; s1++){
            int v = j - s1 + 1;
            vs[s1]  = (v >= 0 && v < 24);
            tau[s1] = (v < 4) ? 0 : ((v < 20) ? 1 : 2);
        }
        #pragma unroll
        for (int r1 = 0; r1 < 3; r1++){
            int u = i - r1 + 1;
            if (u < 0 || u >= 24) continue;
            int rho = (u < 4) ? 0 : ((u < 20) ? 1 : 2);
            #pragma unroll
            for (int s1 = 0; s1 < 3; s1++){
                if (!vs[s1]) continue;
                float tv = D[(size_t)(c1 * 9 + r1 * 3 + s1) * 1152 + b * 576 + p];
                int sl = rho * 3 + tau[s1];
                slot[sl] += tv;
                used |= 1u << sl;
            }
        }
        #pragma unroll
        for (int sl = 0; sl < 9; sl++)
            if (used & (1u << sl)) atomicAdd(&acc[cls * 9 + sl], slot[sl]);
    }
    __syncthreads();
    for (int q = t; q < 1539; q += 256){
        int cls = q / 9, sl = q % 9;
        Zcat16[(size_t)(b * 171 + cls) * 4608 + c1 * 9 + sl] = f2bf(acc[q]);
    }
}

// ---------------- GEMM2 (LDS-staged MFMA, K-split): ypart[s][n][c2] ----------------
// A = Zcat16[384][4608] (rows n, 128-tile), B = Mfull16[512][4608] (rows c2, 64-tile).
// Output rows = n, cols = c2 -> coalesced stores. Grid (3, 8, 24), K-chunk 192.
__launch_bounds__(256)
__global__ void k_gemm2m(const u16* __restrict__ Zcat16, const u16* __restrict__ Mfull16,
                         float* __restrict__ ypart){
    __shared__ u16 As[128 * 64];   // [n][k]
    __shared__ u16 Bs[64 * 64];    // [c2][k]
    int tid  = threadIdx.x;
    int wave = tid >> 6, lane = tid & 63;
    int l16 = lane & 15, quad = lane >> 4;
    int wm = wave >> 1, wn = wave & 1;
    int m0 = blockIdx.x * 128;          // n
    int n0 = blockIdx.y * 64;           // c2
    int kbeg = blockIdx.z * 192;
    int srow = lane >> 3, scol = (lane & 7) * 8;
    f32x4 acc[4][2] = {};
    for (int k0 = kbeg; k0 < kbeg + 192; k0 += 64){
        #pragma unroll
        for (int j = 0; j < 4; j++){
            int ch = wave * 4 + j;
            gload_lds16(Zcat16 + (size_t)(m0 + ch * 8 + srow) * 4608 + k0 + scol, &As[ch * 512]);
        }
        #pragma unroll
        for (int j = 0; j < 2; j++){
            int ch = wave * 2 + j;
            gload_lds16(Mfull16 + (size_t)(n0 + ch * 8 + srow) * 4608 + k0 + scol, &Bs[ch * 512]);
        }
        __syncthreads();
        #pragma unroll
        for (int ks = 0; ks < 2; ks++){
            bf16x8 af[4], bf[2];
            #pragma unroll
            for (int i = 0; i < 4; i++)
                af[i] = *(const bf16x8*)&As[(wm * 64 + i * 16 + l16) * 64 + ks * 32 + quad * 8];
            #pragma unroll
            for (int i = 0; i < 2; i++)
                bf[i] = *(const bf16x8*)&Bs[(wn * 32 + i * 16 + l16) * 64 + ks * 32 + quad * 8];
            #pragma unroll
            for (int mi = 0; mi < 4; mi++)
                #pragma unroll
                for (int ni = 0; ni < 2; ni++)
                    acc[mi][ni] = __builtin_amdgcn_mfma_f32_16x16x32_bf16(af[mi], bf[ni], acc[mi][ni], 0, 0, 0);
        }
        __syncthreads();
    }
    float* yp = ypart + (size_t)blockIdx.z * YN;
    #pragma unroll
    for (int mi = 0; mi < 4; mi++)
        #pragma unroll
        for (int r = 0; r < 4; r++){
            int n = m0 + wm * 64 + mi * 16 + quad * 4 + r;
            if (n >= 342) continue;
            #pragma unroll
            for (int ni = 0; ni < 2; ni++)
                yp[(size_t)n * 512 + n0 + wn * 32 + ni * 16 + l16] = acc[mi][ni][r];
        }
}

// ---------------- fused reduce + final: out1[b,o,cls,c] = w3[o]*(sum ypart + bias) + b3[o] ----------------
__global__ void k_finalr(const float* __restrict__ ypart, const float* __restrict__ bias,
                         const float* __restrict__ w3, const float* __restrict__ b3,
                         float4* __restrict__ out1){
    __shared__ float w3s[77], b3s[77];
    int tid = threadIdx.x;
    if (tid < 77){ w3s[tid] = w3[tid]; b3s[tid] = b3[tid]; }
    __syncthreads();
    int idx = blockIdx.x * 256 + tid;   // YN/4 = 43776
    if (idx >= YN / 4) return;
    int c4 = idx & 127;
    int n  = idx >> 7;                  // b*171 + cls
    const float4* bp = (const float4*)bias;
    float4 sum = bp[c4];
    #pragma unroll 4
    for (int s = 0; s < KS2; s++){
        float4 v = *(const float4*)&ypart[(size_t)s * YN + (size_t)n * 512 + c4 * 4];
        sum.x += v.x; sum.y += v.y; sum.z += v.z; sum.w += v.w;
    }
    int b = n / 171, cls = n % 171;
    size_t base = ((size_t)b * 77 * 171 + cls) * 128 + c4;
    #pragma unroll
    for (int o = 0; o < 77; o++){
        float w = w3s[o], bb = b3s[o];
        out1[base + (size_t)o * 171 * 128] =
            make_float4(w * sum.x + bb, w * sum.y + bb, w * sum.z + bb, w * sum.w + bb);
    }
}

extern "C" void kernel_launch(void* const* d_in, const int* in_sizes, int n_in,
                              void* d_out, int out_size, void* d_ws, size_t ws_size,
                              hipStream_t stream) {
    const float* noise   = (const float*)d_in[0];
    const int*   targets = (const int*)  d_in[1];
    const float* w1      = (const float*)d_in[2];
    const float* b1      = (const float*)d_in[3];
    const float* w2      = (const float*)d_in[4];
    const float* b2      = (const float*)d_in[5];
    const float* w3      = (const float*)d_in[6];
    const float* b3      = (const float*)d_in[7];
    float* out0 = (float*)d_out;
    float* out1 = out0 + OUT0_N;

    char* ws = (char*)d_ws;
    const size_t OFF_ARE  = 0;                        // 4608*768*2   = 7,077,888
    const size_t OFF_X    = 7077888;                  // 1152*768*2   = 1,769,472
    const size_t OFF_D    = OFF_X   + 1769472;        // 4608*1152*4  = 21,233,664 (alias ypart 16,809,984)
    const size_t OFF_MF   = OFF_D   + 21233664;       // 512*4608*2   = 4,718,592
    const size_t OFF_ZC   = OFF_MF  + 4718592;        // 384*4608*2   = 3,538,944
    const size_t OFF_BIAS = OFF_ZC  + 3538944;        // 2048
    const size_t OFF_LAB  = OFF_BIAS + 2048;          // 4608

    u16*   Are    = (u16*)  (ws + OFF_ARE);
    u16*   XbfT   = (u16*)  (ws + OFF_X);
    float* D      = (float*)(ws + OFF_D);
    float* ypart  = (float*)(ws + OFF_D);             // alias: D dead after k_scatter
    u16*   Mfull16= (u16*)  (ws + OFF_MF);
    u16*   Zcat16 = (u16*)  (ws + OFF_ZC);
    float* bias   = (float*)(ws + OFF_BIAS);
    int*   labels = (int*)  (ws + OFF_LAB);

    k_prep  <<<4745, 256, 0, stream>>>(noise, targets, w1, b1, w2, b2,
                                       out0, XbfT, Are, Mfull16, bias, labels, Zcat16);
    k_gemm1 <<<dim3(36, 18), 256, 0, stream>>>(Are, XbfT, D);
    k_scatter<<<1024, 256, 0, stream>>>(D, labels, Zcat16);
    k_gemm2m<<<dim3(3, 8, KS2), 256, 0, stream>>>(Zcat16, Mfull16, ypart);
    k_finalr<<<171, 256, 0, stream>>>(ypart, bias, w3, b3, (float4*)out1);
}